// Round 2
// baseline (366.607 us; speedup 1.0000x reference)
//
#include <hip/hip_runtime.h>
#include <hip/hip_bf16.h>

#define BT 64
#define C  256
#define H  64
#define W  64
#define J  17
#define NP 4
#define HID 128

// bilinear sample of one channel plane p[H][W] at (x, y) in pixel coords,
// padding_mode='zeros', align_corners=True semantics (coords already mapped).
__device__ __forceinline__ float bilin_one(const float* __restrict__ p, float x, float y) {
    float x0f = floorf(x), y0f = floorf(y);
    int x0 = (int)x0f, y0 = (int)y0f;
    int x1 = x0 + 1,  y1 = y0 + 1;
    float wx1 = x - x0f, wx0 = 1.0f - wx1;
    float wy1 = y - y0f, wy0 = 1.0f - wy1;
    bool vx0 = ((unsigned)x0 < (unsigned)W);
    bool vx1 = ((unsigned)x1 < (unsigned)W);
    bool vy0 = ((unsigned)y0 < (unsigned)H);
    bool vy1 = ((unsigned)y1 < (unsigned)H);
    float v00 = (vx0 && vy0) ? p[y0 * W + x0] : 0.0f;
    float v10 = (vx1 && vy0) ? p[y0 * W + x1] : 0.0f;
    float v01 = (vx0 && vy1) ? p[y1 * W + x0] : 0.0f;
    float v11 = (vx1 && vy1) ? p[y1 * W + x1] : 0.0f;
    return v00 * (wx0 * wy0) + v10 * (wx1 * wy0)
         + v01 * (wx0 * wy1) + v11 * (wx1 * wy1);
}

// ---- KA: transpose w1 [HID][C] -> w1T [C][HID] in workspace ----
__global__ __launch_bounds__(256) void ka_transpose_w1(
        const float* __restrict__ w1, float* __restrict__ w1T) {
    const int o = blockIdx.x;       // 0..HID-1
    const int c = threadIdx.x;      // 0..C-1
    // read coalesced along c, write strided (tiny: 128 KB total, one-time)
    w1T[c * HID + o] = w1[o * C + c];
}

// ---- KB: seed sample + MLP -> pixel-space coords [BJ][NP][2] in ws ----
__global__ __launch_bounds__(256) void kb_seed_mlp(
        const float* __restrict__ feat,   // [BT, C, H, W]
        const float* __restrict__ kp,     // [BT, J, 2]
        const float* __restrict__ w1T,    // [C, HID] (ws)
        const float* __restrict__ b1,     // [HID]
        const float* __restrict__ w2,     // [2*NP, HID]
        const float* __restrict__ b2,     // [2*NP]
        float* __restrict__ coords)       // [BT*J, NP, 2] pixel coords (ws)
{
    const int bj  = blockIdx.x;
    const int b   = bj / J;
    const int tid = threadIdx.x;

    __shared__ float s_seed[C];
    __shared__ float s_h[HID];

    const float gx = kp[bj * 2 + 0];
    const float gy = kp[bj * 2 + 1];
    const float px = (gx + 1.0f) * 0.5f * (float)(W - 1);
    const float py = (gy + 1.0f) * 0.5f * (float)(H - 1);

    const float* plane = feat + ((size_t)b * C + tid) * (H * W);
    s_seed[tid] = bilin_one(plane, px, py);
    __syncthreads();

    if (tid < HID) {
        float acc = b1[tid];
        // coalesced: per c, lanes read w1T[c*HID + tid] (contiguous across lanes)
        #pragma unroll 8
        for (int c = 0; c < C; ++c) {
            acc += w1T[c * HID + tid] * s_seed[c];
        }
        s_h[tid] = fmaxf(acc, 0.0f);
    }
    __syncthreads();

    if (tid < 2 * NP) {
        const float4* wrow = (const float4*)(w2 + tid * HID);
        float acc = b2[tid];
        #pragma unroll 8
        for (int k4 = 0; k4 < HID / 4; ++k4) {
            float4 wv = wrow[k4];
            acc += wv.x * s_h[k4 * 4 + 0];
            acc += wv.y * s_h[k4 * 4 + 1];
            acc += wv.z * s_h[k4 * 4 + 2];
            acc += wv.w * s_h[k4 * 4 + 3];
        }
        // tid = 2*n + axis ; axis 0 = x, 1 = y
        const int axis = tid & 1;
        const float g     = axis ? gy : gx;
        const float scale = axis ? (2.0f / (float)(H - 1)) : (2.0f / (float)(W - 1));
        const float dim1  = axis ? (float)(H - 1) : (float)(W - 1);
        const float ng  = g + acc * scale;
        const float pix = (ng + 1.0f) * 0.5f * dim1;
        coords[bj * (2 * NP) + tid] = pix;
    }
}

// ---- KC: deformed sampling, one block per (bj, n), thread = channel ----
__global__ __launch_bounds__(256) void kc_sample(
        const float* __restrict__ feat,    // [BT, C, H, W]
        const float* __restrict__ coords,  // [BT*J, NP, 2] pixel coords (ws)
        float* __restrict__ out)           // [BT, J, NP*C]
{
    const int id = blockIdx.x;     // bj * NP + n
    const int bj = id >> 2;
    const int b  = bj / J;
    const int c  = threadIdx.x;

    const float px = coords[id * 2 + 0];
    const float py = coords[id * 2 + 1];

    const float* plane = feat + ((size_t)b * C + c) * (H * W);
    out[(size_t)id * C + c] = bilin_one(plane, px, py);
}

extern "C" void kernel_launch(void* const* d_in, const int* in_sizes, int n_in,
                              void* d_out, int out_size, void* d_ws, size_t ws_size,
                              hipStream_t stream) {
    const float* feat = (const float*)d_in[0];
    const float* kp   = (const float*)d_in[1];
    const float* w1   = (const float*)d_in[2];
    const float* b1   = (const float*)d_in[3];
    const float* w2   = (const float*)d_in[4];
    const float* b2   = (const float*)d_in[5];
    float* out = (float*)d_out;

    float* w1T    = (float*)d_ws;                  // C*HID floats = 128 KB
    float* coords = w1T + (size_t)C * HID;         // BT*J*NP*2 floats = 34 KB

    ka_transpose_w1<<<dim3(HID), dim3(C), 0, stream>>>(w1, w1T);
    kb_seed_mlp<<<dim3(BT * J), dim3(C), 0, stream>>>(feat, kp, w1T, b1, w2, b2, coords);
    kc_sample<<<dim3(BT * J * NP), dim3(C), 0, stream>>>(feat, coords, out);
}

// Round 3
// 357.509 us; speedup vs baseline: 1.0254x; 1.0254x over previous
//
#include <hip/hip_runtime.h>
#include <hip/hip_bf16.h>

#define BT 64
#define C  256
#define H  64
#define W  64
#define J  17
#define NP 4
#define HID 128

// bilinear sample of one channel plane p[H][W] at (x, y) in pixel coords,
// padding_mode='zeros', align_corners=True semantics (coords already mapped).
__device__ __forceinline__ float bilin_one(const float* __restrict__ p, float x, float y) {
    float x0f = floorf(x), y0f = floorf(y);
    int x0 = (int)x0f, y0 = (int)y0f;
    int x1 = x0 + 1,  y1 = y0 + 1;
    float wx1 = x - x0f, wx0 = 1.0f - wx1;
    float wy1 = y - y0f, wy0 = 1.0f - wy1;
    bool vx0 = ((unsigned)x0 < (unsigned)W);
    bool vx1 = ((unsigned)x1 < (unsigned)W);
    bool vy0 = ((unsigned)y0 < (unsigned)H);
    bool vy1 = ((unsigned)y1 < (unsigned)H);
    float v00 = (vx0 && vy0) ? p[y0 * W + x0] : 0.0f;
    float v10 = (vx1 && vy0) ? p[y0 * W + x1] : 0.0f;
    float v01 = (vx0 && vy1) ? p[y1 * W + x0] : 0.0f;
    float v11 = (vx1 && vy1) ? p[y1 * W + x1] : 0.0f;
    return v00 * (wx0 * wy0) + v10 * (wx1 * wy0)
         + v01 * (wx0 * wy1) + v11 * (wx1 * wy1);
}

// ---- KA: transpose w1 [HID][C] -> w1T [C][HID] in workspace (128 KB, ~2 us) ----
__global__ __launch_bounds__(256) void ka_transpose_w1(
        const float* __restrict__ w1, float* __restrict__ w1T) {
    const int o = blockIdx.x;       // 0..HID-1
    const int c = threadIdx.x;      // 0..C-1
    w1T[c * HID + o] = w1[o * C + c];
}

// ---- KF: fully fused seed-sample + MLP + deformed sampling ----
// One block per (b, j); thread = channel. Seed gather warms L1/L2 with the
// same lines the deformed gathers read (offsets are tiny), so phase 4 mostly
// hits cache.
__global__ __launch_bounds__(256) void kf_fused(
        const float* __restrict__ feat,   // [BT, C, H, W]
        const float* __restrict__ kp,     // [BT, J, 2]
        const float* __restrict__ w1T,    // [C, HID] (ws)
        const float* __restrict__ b1,     // [HID]
        const float* __restrict__ w2,     // [2*NP, HID]
        const float* __restrict__ b2,     // [2*NP]
        float* __restrict__ out)          // [BT, J, NP, C]
{
    const int bj  = blockIdx.x;
    const int b   = bj / J;
    const int tid = threadIdx.x;

    __shared__ float s_seed[C];
    __shared__ float s_h[HID];
    __shared__ float s_pix[2 * NP];      // pixel-space coords of the 4 points

    const float gx = kp[bj * 2 + 0];
    const float gy = kp[bj * 2 + 1];
    const float px = (gx + 1.0f) * 0.5f * (float)(W - 1);
    const float py = (gy + 1.0f) * 0.5f * (float)(H - 1);

    const float* plane = feat + ((size_t)b * C + tid) * (H * W);

    // ---- 1. seed sample ----
    s_seed[tid] = bilin_one(plane, px, py);
    __syncthreads();

    // ---- 2. layer 1: coalesced reads of w1T (lanes contiguous over HID) ----
    if (tid < HID) {
        float acc = b1[tid];
        #pragma unroll 8
        for (int c = 0; c < C; ++c) {
            acc += w1T[c * HID + tid] * s_seed[c];
        }
        s_h[tid] = fmaxf(acc, 0.0f);
    }
    __syncthreads();

    // ---- 3. layer 2: 8 outputs -> pixel coords ----
    if (tid < 2 * NP) {
        const float4* wrow = (const float4*)(w2 + tid * HID);
        float acc = b2[tid];
        #pragma unroll 8
        for (int k4 = 0; k4 < HID / 4; ++k4) {
            float4 wv = wrow[k4];
            acc += wv.x * s_h[k4 * 4 + 0];
            acc += wv.y * s_h[k4 * 4 + 1];
            acc += wv.z * s_h[k4 * 4 + 2];
            acc += wv.w * s_h[k4 * 4 + 3];
        }
        // tid = 2*n + axis ; axis 0 = x (W), 1 = y (H)
        const int axis = tid & 1;
        const float g     = axis ? gy : gx;
        const float scale = axis ? (2.0f / (float)(H - 1)) : (2.0f / (float)(W - 1));
        const float dim1  = axis ? (float)(H - 1) : (float)(W - 1);
        const float ng  = g + acc * scale;
        s_pix[tid] = (ng + 1.0f) * 0.5f * dim1;
    }
    __syncthreads();

    // ---- 4. deformed samples: 4 points, thread = channel, coalesced stores ----
    float* outp = out + (size_t)bj * NP * C + tid;
    #pragma unroll
    for (int n = 0; n < NP; ++n) {
        outp[n * C] = bilin_one(plane, s_pix[2 * n + 0], s_pix[2 * n + 1]);
    }
}

extern "C" void kernel_launch(void* const* d_in, const int* in_sizes, int n_in,
                              void* d_out, int out_size, void* d_ws, size_t ws_size,
                              hipStream_t stream) {
    const float* feat = (const float*)d_in[0];
    const float* kp   = (const float*)d_in[1];
    const float* w1   = (const float*)d_in[2];
    const float* b1   = (const float*)d_in[3];
    const float* w2   = (const float*)d_in[4];
    const float* b2   = (const float*)d_in[5];
    float* out = (float*)d_out;

    float* w1T = (float*)d_ws;     // C*HID floats = 128 KB

    ka_transpose_w1<<<dim3(HID), dim3(C), 0, stream>>>(w1, w1T);
    kf_fused<<<dim3(BT * J), dim3(C), 0, stream>>>(feat, kp, w1T, b1, w2, b2, out);
}